// Round 1
// baseline (377.686 us; speedup 1.0000x reference)
//
#include <hip/hip_runtime.h>

// Problem constants (fixed by the reference)
constexpr int BATCH  = 32;
constexpr int TIME   = 1024;
constexpr int IN_DIM = 512;
constexpr int HIDDEN = 512;

constexpr int GM = BATCH * TIME;   // 32768  (GEMM M)
constexpr int GN = HIDDEN;         // 512    (GEMM N)
constexpr int GK = IN_DIM;         // 512    (GEMM K)

#define GLOBAL_AS __attribute__((address_space(1)))
#define LDS_AS    __attribute__((address_space(3)))

// s_waitcnt immediate: vmcnt[3:0]|expcnt(no-wait)|lgkmcnt(no-wait)|vmcnt[5:4]
#define WAITCNT_VMCNT(n) (((n) & 15) | (((n) >> 4) << 14) | (0x7 << 4) | (0xF << 8))

// ---------------- GEMM geometry: champion config, KEEP VERBATIM ----------------
// 128x128x16, 256 threads, 8x8 microtile, BOTH operands via LDS.
// (203-208us standalone, VALUBusy 68%, VGPR 52.)
constexpr int BM = 128;
constexpr int BN = 128;
constexpr int BK = 16;
constexpr int LDAs = BM + 4;   // padded (2-way LDS alias only = free)
constexpr int LDBs = BN + 4;

constexpr int NGEMM_M = GM / BM;             // 256
constexpr int NGEMM_N = GN / BN;             // 4
constexpr int NGEMM   = NGEMM_M * NGEMM_N;   // 1024 GEMM-role blocks
constexpr int NSCAN   = BATCH * (HIDDEN/64); // 256  scan-role blocks

// ---------------- Scan geometry ----------------
// Ring shrunk 128KB -> 16KB so it UNIONS into the GEMM smem footprint:
// kernel LDS stays 16.9KB => GEMM co-residency (4 blocks/CU of 8 capacity)
// is untouched and all 1280 blocks are simultaneously resident (no deadlock
// possible: GEMM blocks never wait).
constexpr int SCH   = 32;            // timesteps per chunk
constexpr int NCHK  = TIME / SCH;    // 32 chunks
constexpr int RINGC = 2;             // double-buffered ring (2 chunks = 16KB)

static_assert(RINGC * SCH * 64 <= BK * LDAs + BK * LDBs, "ring must fit GEMM smem");

// Per-tile ready flags: flag[g] set by GEMM block g = (b*8+tt) + 256*(h0>>7).
// Zeroed by a leading kernel each launch (graph-replay safe).
__device__ int g_flags[NGEMM];

__global__ void zero_flags_kernel() {
    const int i = blockIdx.x * 256 + (int)threadIdx.x;
    if (i < NGEMM) g_flags[i] = 0;
}

__global__ __launch_bounds__(256) void fused_kernel(
    const float* __restrict__ A,     // [GM, GK] spikes
    const float* __restrict__ B,     // [GK, GN] W
    const float* __restrict__ bias,  // [GN]
    float* __restrict__ I_in,        // [GM, GN] workspace
    float* __restrict__ O)           // [B, T, H] output spikes
{
    __shared__ __align__(16) float smem[BK * LDAs + BK * LDBs];  // 16896 B
    __shared__ int prod_c;                 // scan: chunks fully landed in LDS
    __shared__ int cons_c;                 // scan: chunks consumed

    if (blockIdx.x < (unsigned)NGEMM) {
        // =========================================================
        // GEMM role — champion math VERBATIM; linear id preserves the
        // original (256,4) mapping: m fast => same-A blocks 256 apart
        // -> same XCD (L2 reuse).
        // =========================================================
        float* As = smem;
        float* Bs = smem + BK * LDAs;

        const int g   = blockIdx.x;
        const int tid = threadIdx.x;           // 0..255
        const int bm  = (g & (NGEMM_M - 1)) * BM;
        const int bn  = (g >> 8) * BN;

        const int w    = tid >> 6;
        const int lane = tid & 63;
        const int row0 = (w >> 1) * 64 + (lane >> 3) * 8;
        const int col0 = (w & 1)  * 64 + (lane & 7)  * 8;

        const int ar0 = tid >> 2;              // A row for quad 0 (0..63), +64
        const int ac  = (tid & 3) << 2;        // A col within K-tile (0..12)
        const int br0 = tid >> 5;              // B row for quad 0 (0..7), +8
        const int bc  = (tid & 31) << 2;       // B col within N-tile (0..124)

        float acc[8][8];
        #pragma unroll
        for (int i = 0; i < 8; ++i)
            #pragma unroll
            for (int j = 0; j < 8; ++j) acc[i][j] = 0.0f;

        #pragma unroll 1
        for (int k0 = 0; k0 < GK; k0 += BK) {
            float4 va0 = *reinterpret_cast<const float4*>(A + (size_t)(bm + ar0) * GK + k0 + ac);
            float4 va1 = *reinterpret_cast<const float4*>(A + (size_t)(bm + ar0 + 64) * GK + k0 + ac);
            float4 vb0 = *reinterpret_cast<const float4*>(B + (size_t)(k0 + br0) * GN + bn + bc);
            float4 vb1 = *reinterpret_cast<const float4*>(B + (size_t)(k0 + br0 + 8) * GN + bn + bc);

            __syncthreads();   // previous tile's compute done before overwrite

            As[(ac + 0) * LDAs + ar0] = va0.x;
            As[(ac + 1) * LDAs + ar0] = va0.y;
            As[(ac + 2) * LDAs + ar0] = va0.z;
            As[(ac + 3) * LDAs + ar0] = va0.w;
            As[(ac + 0) * LDAs + ar0 + 64] = va1.x;
            As[(ac + 1) * LDAs + ar0 + 64] = va1.y;
            As[(ac + 2) * LDAs + ar0 + 64] = va1.z;
            As[(ac + 3) * LDAs + ar0 + 64] = va1.w;
            *reinterpret_cast<float4*>(&Bs[br0 * LDBs + bc]) = vb0;
            *reinterpret_cast<float4*>(&Bs[(br0 + 8) * LDBs + bc]) = vb1;

            __syncthreads();

            #pragma unroll
            for (int kk = 0; kk < BK; ++kk) {
                const float4 a0 = *reinterpret_cast<const float4*>(&As[kk * LDAs + row0]);
                const float4 a1 = *reinterpret_cast<const float4*>(&As[kk * LDAs + row0 + 4]);
                const float4 b0 = *reinterpret_cast<const float4*>(&Bs[kk * LDBs + col0]);
                const float4 b1 = *reinterpret_cast<const float4*>(&Bs[kk * LDBs + col0 + 4]);
                const float arr[8] = {a0.x, a0.y, a0.z, a0.w, a1.x, a1.y, a1.z, a1.w};
                const float brr[8] = {b0.x, b0.y, b0.z, b0.w, b1.x, b1.y, b1.z, b1.w};
                #pragma unroll
                for (int i = 0; i < 8; ++i)
                    #pragma unroll
                    for (int j = 0; j < 8; ++j)
                        acc[i][j] = fmaf(arr[i], brr[j], acc[i][j]);
            }
        }

        // ---- epilogue: add bias (separate fp32 add, like numpy), store ----
        #pragma unroll
        for (int i = 0; i < 8; ++i) {
            const size_t r = (size_t)(bm + row0 + i);
            #pragma unroll
            for (int j = 0; j < 8; j += 4) {
                float4 v;
                v.x = __fadd_rn(acc[i][j + 0], bias[bn + col0 + j + 0]);
                v.y = __fadd_rn(acc[i][j + 1], bias[bn + col0 + j + 1]);
                v.z = __fadd_rn(acc[i][j + 2], bias[bn + col0 + j + 2]);
                v.w = __fadd_rn(acc[i][j + 3], bias[bn + col0 + j + 3]);
                *reinterpret_cast<float4*>(&I_in[r * GN + bn + col0 + j]) = v;
            }
        }

        // ---- publish tile: barrier drains every thread's stores (vmcnt0),
        // then ONE agent-release fence (single buffer_wbl2 flushes the whole
        // block's dirty C lines from this XCD's L2) + relaxed flag store.
        __syncthreads();
        if (tid == 0) {
            __builtin_amdgcn_fence(__ATOMIC_RELEASE, "agent");
            __hip_atomic_store(&g_flags[g], 1, __ATOMIC_RELAXED,
                               __HIP_MEMORY_SCOPE_AGENT);
        }
        return;
    }

    // =========================================================
    // Scan role — champion producer/consumer protocol (width-4 DMA,
    // 32 DMAs/chunk, vmcnt(32) retirement, RELEASE atomics) with:
    //   * ring 128KB -> 16KB (RINGC=2) to union into GEMM smem
    //   * producer gated per 128-t tile on g_flags (RELAXED poll +
    //     one agent-acquire fence per tile; acquire-per-poll would
    //     spray buffer_inv and thrash the L2 the GEMM lives on)
    //   * consumer batches the 32 ds_reads into regs before the
    //     dependent chain (tests the ds_read-latency-serialization
    //     theory of the standalone 87us)
    // Arithmetic order and constants are bit-identical to champion.
    // =========================================================
    if (threadIdx.x == 0) { prod_c = 0; cons_c = 0; }
    __syncthreads();                       // all 4 waves reach this barrier
    if (threadIdx.x >= 128) return;        // waves 2,3 exit after barrier

    float* ring = smem;                    // [RINGC*SCH][64] floats = 16 KB

    const int sb   = (int)blockIdx.x - NGEMM;   // 0..255
    const int b    = sb >> 3;                   // 8 blocks per batch row
    const int h0   = (sb & 7) * 64;
    const int wave = threadIdx.x >> 6;
    const int lane = threadIdx.x & 63;
    const size_t base = (size_t)b * TIME * HIDDEN + h0;
    const int fbase = b * 8 + ((h0 >> 7) << 8); // flag id = (b*8+tt) + 256*ntile

    if (wave == 0) {
        // ---------------- producer ----------------
        const float* g0 = I_in + base + lane;
        #pragma unroll 1
        for (int c = 0; c < NCHK; ++c) {
            if ((c & 3) == 0) {            // new 128-t GEMM tile needed
                const int f = fbase + (c >> 2);
                while (__hip_atomic_load(&g_flags[f], __ATOMIC_RELAXED,
                                         __HIP_MEMORY_SCOPE_AGENT) == 0)
                    __builtin_amdgcn_s_sleep(8);
                __builtin_amdgcn_fence(__ATOMIC_ACQUIRE, "agent");
            }
            if (c >= RINGC) {              // backpressure: live slot
                while (__hip_atomic_load(&cons_c, __ATOMIC_ACQUIRE,
                                         __HIP_MEMORY_SCOPE_WORKGROUP)
                       <= c - RINGC)
                    __builtin_amdgcn_s_sleep(1);
            }
            const int slot = (c & (RINGC - 1)) * SCH;
            #pragma unroll
            for (int u = 0; u < SCH; ++u) {
                const int t = c * SCH + u;
                __builtin_amdgcn_global_load_lds(
                    (GLOBAL_AS const void*)(g0 + (size_t)t * HIDDEN),
                    (LDS_AS void*)&ring[(slot + u) * 64], 4, 0, 0);
            }
            // all but the newest 32 loads have landed => chunks <= c-1 done
            __builtin_amdgcn_s_waitcnt(WAITCNT_VMCNT(32));
            __hip_atomic_store(&prod_c, c, __ATOMIC_RELEASE,
                               __HIP_MEMORY_SCOPE_WORKGROUP);
        }
        __builtin_amdgcn_s_waitcnt(WAITCNT_VMCNT(0));
        __hip_atomic_store(&prod_c, NCHK, __ATOMIC_RELEASE,
                           __HIP_MEMORY_SCOPE_WORKGROUP);
    } else {
        // ---------------- consumer ----------------
        // exp(-0.05), exp(-0.2) correctly rounded fp32 (match np.exp)
        const float am = 0.95122942450071400910f;
        const float as = 0.81873075307798185867f;
        float v = 0.0f, s = 0.0f;
        float* o0 = O + base + lane;

        #pragma unroll 1
        for (int c = 0; c < NCHK; ++c) {
            while (__hip_atomic_load(&prod_c, __ATOMIC_ACQUIRE,
                                     __HIP_MEMORY_SCOPE_WORKGROUP) < c + 1)
                __builtin_amdgcn_s_sleep(1);
            const int slot = (c & (RINGC - 1)) * SCH;
            // batch all 32 LDS reads first (bank = lane%32 -> 2-way = free),
            // then run the dependent chain on registers
            float x[SCH];
            #pragma unroll
            for (int u = 0; u < SCH; ++u)
                x[u] = ring[(slot + u) * 64 + lane];
            #pragma unroll
            for (int u = 0; u < SCH; ++u) {
                // separate mul/add roundings to match numpy (no FMA fusion)
                s = __fadd_rn(__fmul_rn(as, s), x[u]);
                v = __fadd_rn(__fmul_rn(am, v), s);
                const float o = (v > 1.0f) ? 1.0f : 0.0f;
                v = __fsub_rn(v, o);
                o0[(size_t)(c * SCH + u) * HIDDEN] = o;
            }
            __hip_atomic_store(&cons_c, c + 1, __ATOMIC_RELEASE,
                               __HIP_MEMORY_SCOPE_WORKGROUP);
        }
    }
}

extern "C" void kernel_launch(void* const* d_in, const int* in_sizes, int n_in,
                              void* d_out, int out_size, void* d_ws, size_t ws_size,
                              hipStream_t stream) {
    const float* spikes = (const float*)d_in[0];   // [32, 1024, 512]
    const float* W      = (const float*)d_in[1];   // [512, 512]
    const float* bias   = (const float*)d_in[2];   // [512]
    float* out  = (float*)d_out;                   // [32, 1024, 512]
    float* I_in = (float*)d_ws;                    // 64 MiB scratch

    zero_flags_kernel<<<dim3((NGEMM + 255) / 256), 256, 0, stream>>>();
    fused_kernel<<<dim3(NGEMM + NSCAN), 256, 0, stream>>>(spikes, W, bias, I_in, out);
}

// Round 3
// 352.873 us; speedup vs baseline: 1.0703x; 1.0703x over previous
//
#include <hip/hip_runtime.h>

// Problem constants (fixed by the reference)
constexpr int BATCH  = 32;
constexpr int TIME   = 1024;
constexpr int IN_DIM = 512;
constexpr int HIDDEN = 512;

constexpr int GM = BATCH * TIME;   // 32768  (GEMM M)
constexpr int GN = HIDDEN;         // 512    (GEMM N)
constexpr int GK = IN_DIM;         // 512    (GEMM K)

#define GLOBAL_AS __attribute__((address_space(1)))
#define LDS_AS    __attribute__((address_space(3)))

// s_waitcnt immediate: vmcnt[3:0]|expcnt(no-wait)|lgkmcnt(no-wait)|vmcnt[5:4]
#define WAITCNT_VMCNT(n) (((n) & 15) | (((n) >> 4) << 14) | (0x7 << 4) | (0xF << 8))

// ---------------- GEMM geometry: champion config, KEEP VERBATIM ----------------
// 128x128x16, 256 threads, 8x8 microtile, BOTH operands via LDS.
// (203-208us standalone, VALUBusy 68%, VGPR 52.)
constexpr int BM = 128;
constexpr int BN = 128;
constexpr int BK = 16;
constexpr int LDAs = BM + 4;   // padded (2-way LDS alias only = free)
constexpr int LDBs = BN + 4;

constexpr int NGEMM_M = GM / BM;             // 256 m-tiles = 32 b x 8 tt
constexpr int NGEMM_N = GN / BN;             // 4
constexpr int NGEMM   = NGEMM_M * NGEMM_N;   // 1024 GEMM-role blocks
constexpr int NSCAN   = BATCH * (HIDDEN/64); // 256  scan-role blocks

// ---------------- Scan geometry ----------------
constexpr int SCH   = 32;            // timesteps per chunk
constexpr int NCHK  = TIME / SCH;    // 32 chunks
constexpr int RINGC = 2;             // double-buffered ring (2 chunks = 16KB)

static_assert(RINGC * SCH * 64 <= BK * LDAs + BK * LDBs, "ring must fit GEMM smem");

// Per-tile ready flags, zeroed by a leading kernel each launch (graph-safe).
// tt-major indexing: flag id g = tt*128 + n*32 + b.
__device__ int g_flags[NGEMM];

__global__ void zero_flags_kernel() {
    const int i = blockIdx.x * 256 + (int)threadIdx.x;
    if (i < NGEMM) g_flags[i] = 0;
}

__global__ __launch_bounds__(256) void fused_kernel(
    const float* __restrict__ A,     // [GM, GK] spikes
    const float* __restrict__ B,     // [GK, GN] W
    const float* __restrict__ bias,  // [GN]
    float* __restrict__ I_in,        // [GM, GN] workspace
    float* __restrict__ O)           // [B, T, H] output spikes
{
    __shared__ __align__(16) float smem[BK * LDAs + BK * LDBs];  // 16896 B
    __shared__ int prod_c;                 // scan: chunks fully landed in LDS
    __shared__ int cons_c;                 // scan: chunks consumed

    if (blockIdx.x < (unsigned)NGEMM) {
        // =========================================================
        // GEMM role — champion math VERBATIM.
        // tt-major block mapping + wave-priority cascade.
        //   g = tt*128 + n*32 + b  (tt = t-slice 0..7, n = N-tile, b = batch)
        //   * A-tile-sharing blocks (same b,tt; n=0..3) are 32 ids apart:
        //     32 % 8 == 0 -> same XCD -> L2 reuse preserved.
        //   * prio = 3 - (tt>>1): per-SIMD issue arbitration serializes the
        //     4 co-resident tt-groups -> tile completion staggers in tt
        //     order while total issue slots (GEMM time) stay constant.
        //   s_setprio requires an IMMEDIATE (R2 compile fail) -> uniform
        //   scalar branch to constant call sites.
        // =========================================================
        const int g   = blockIdx.x;
        const int tt  = g >> 7;                // 0..7
        const int idx = g & 127;
        const int n   = idx >> 5;              // 0..3
        const int b   = idx & 31;              // 0..31

        switch (tt >> 1) {                     // wave-uniform scalar branch
            case 0: __builtin_amdgcn_s_setprio(3); break;
            case 1: __builtin_amdgcn_s_setprio(2); break;
            case 2: __builtin_amdgcn_s_setprio(1); break;
            default: __builtin_amdgcn_s_setprio(0); break;
        }

        float* As = smem;
        float* Bs = smem + BK * LDAs;

        const int tid = threadIdx.x;           // 0..255
        const int bm  = (b * 8 + tt) * BM;     // m-tile = (b, t-slice)
        const int bn  = n * BN;

        const int w    = tid >> 6;
        const int lane = tid & 63;
        const int row0 = (w >> 1) * 64 + (lane >> 3) * 8;
        const int col0 = (w & 1)  * 64 + (lane & 7)  * 8;

        const int ar0 = tid >> 2;              // A row for quad 0 (0..63), +64
        const int ac  = (tid & 3) << 2;        // A col within K-tile (0..12)
        const int br0 = tid >> 5;              // B row for quad 0 (0..7), +8
        const int bc  = (tid & 31) << 2;       // B col within N-tile (0..124)

        float acc[8][8];
        #pragma unroll
        for (int i = 0; i < 8; ++i)
            #pragma unroll
            for (int j = 0; j < 8; ++j) acc[i][j] = 0.0f;

        #pragma unroll 1
        for (int k0 = 0; k0 < GK; k0 += BK) {
            float4 va0 = *reinterpret_cast<const float4*>(A + (size_t)(bm + ar0) * GK + k0 + ac);
            float4 va1 = *reinterpret_cast<const float4*>(A + (size_t)(bm + ar0 + 64) * GK + k0 + ac);
            float4 vb0 = *reinterpret_cast<const float4*>(B + (size_t)(k0 + br0) * GN + bn + bc);
            float4 vb1 = *reinterpret_cast<const float4*>(B + (size_t)(k0 + br0 + 8) * GN + bn + bc);

            __syncthreads();   // previous tile's compute done before overwrite

            As[(ac + 0) * LDAs + ar0] = va0.x;
            As[(ac + 1) * LDAs + ar0] = va0.y;
            As[(ac + 2) * LDAs + ar0] = va0.z;
            As[(ac + 3) * LDAs + ar0] = va0.w;
            As[(ac + 0) * LDAs + ar0 + 64] = va1.x;
            As[(ac + 1) * LDAs + ar0 + 64] = va1.y;
            As[(ac + 2) * LDAs + ar0 + 64] = va1.z;
            As[(ac + 3) * LDAs + ar0 + 64] = va1.w;
            *reinterpret_cast<float4*>(&Bs[br0 * LDBs + bc]) = vb0;
            *reinterpret_cast<float4*>(&Bs[(br0 + 8) * LDBs + bc]) = vb1;

            __syncthreads();

            #pragma unroll
            for (int kk = 0; kk < BK; ++kk) {
                const float4 a0 = *reinterpret_cast<const float4*>(&As[kk * LDAs + row0]);
                const float4 a1 = *reinterpret_cast<const float4*>(&As[kk * LDAs + row0 + 4]);
                const float4 b0 = *reinterpret_cast<const float4*>(&Bs[kk * LDBs + col0]);
                const float4 b1 = *reinterpret_cast<const float4*>(&Bs[kk * LDBs + col0 + 4]);
                const float arr[8] = {a0.x, a0.y, a0.z, a0.w, a1.x, a1.y, a1.z, a1.w};
                const float brr[8] = {b0.x, b0.y, b0.z, b0.w, b1.x, b1.y, b1.z, b1.w};
                #pragma unroll
                for (int i = 0; i < 8; ++i)
                    #pragma unroll
                    for (int j = 0; j < 8; ++j)
                        acc[i][j] = fmaf(arr[i], brr[j], acc[i][j]);
            }
        }

        // ---- epilogue: add bias (separate fp32 add, like numpy), store ----
        #pragma unroll
        for (int i = 0; i < 8; ++i) {
            const size_t r = (size_t)(bm + row0 + i);
            #pragma unroll
            for (int j = 0; j < 8; j += 4) {
                float4 v;
                v.x = __fadd_rn(acc[i][j + 0], bias[bn + col0 + j + 0]);
                v.y = __fadd_rn(acc[i][j + 1], bias[bn + col0 + j + 1]);
                v.z = __fadd_rn(acc[i][j + 2], bias[bn + col0 + j + 2]);
                v.w = __fadd_rn(acc[i][j + 3], bias[bn + col0 + j + 3]);
                *reinterpret_cast<float4*>(&I_in[r * GN + bn + col0 + j]) = v;
            }
        }

        // ---- publish tile: barrier drains every thread's stores (vmcnt0),
        // then ONE agent-release fence + relaxed flag store.
        __syncthreads();
        if (tid == 0) {
            __builtin_amdgcn_fence(__ATOMIC_RELEASE, "agent");
            __hip_atomic_store(&g_flags[g], 1, __ATOMIC_RELAXED,
                               __HIP_MEMORY_SCOPE_AGENT);
        }
        return;
    }

    // =========================================================
    // Scan role — champion producer/consumer protocol (width-4 DMA,
    // 32 DMAs/chunk, vmcnt(32) retirement, RELEASE atomics), ring
    // unioned into GEMM smem, per-tile flag gating, batched ds_reads.
    // Scan waves at prio 3 so they never starve behind GEMM waves
    // (they issue rarely — sleeps + latency chain — so GEMM cost ~0).
    // Arithmetic order and constants are bit-identical to champion.
    // =========================================================
    __builtin_amdgcn_s_setprio(3);

    if (threadIdx.x == 0) { prod_c = 0; cons_c = 0; }
    __syncthreads();                       // all 4 waves reach this barrier
    if (threadIdx.x >= 128) return;        // waves 2,3 exit after barrier

    float* ring = smem;                    // [RINGC*SCH][64] floats = 16 KB

    const int sb   = (int)blockIdx.x - NGEMM;   // 0..255
    const int b    = sb >> 3;                   // 8 blocks per batch row
    const int h0   = (sb & 7) * 64;
    const int wave = threadIdx.x >> 6;
    const int lane = threadIdx.x & 63;
    const size_t base = (size_t)b * TIME * HIDDEN + h0;
    // flag id for t-slice tt: f = tt*128 + n*32 + b, n = h0/128
    const int fbase = (h0 >> 7) * 32 + b;

    if (wave == 0) {
        // ---------------- producer ----------------
        const float* g0 = I_in + base + lane;
        #pragma unroll 1
        for (int c = 0; c < NCHK; ++c) {
            if ((c & 3) == 0) {            // new 128-t GEMM tile needed
                const int f = (c >> 2) * 128 + fbase;
                while (__hip_atomic_load(&g_flags[f], __ATOMIC_RELAXED,
                                         __HIP_MEMORY_SCOPE_AGENT) == 0)
                    __builtin_amdgcn_s_sleep(8);
                __builtin_amdgcn_fence(__ATOMIC_ACQUIRE, "agent");
            }
            if (c >= RINGC) {              // backpressure: live slot
                while (__hip_atomic_load(&cons_c, __ATOMIC_ACQUIRE,
                                         __HIP_MEMORY_SCOPE_WORKGROUP)
                       <= c - RINGC)
                    __builtin_amdgcn_s_sleep(1);
            }
            const int slot = (c & (RINGC - 1)) * SCH;
            #pragma unroll
            for (int u = 0; u < SCH; ++u) {
                const int t = c * SCH + u;
                __builtin_amdgcn_global_load_lds(
                    (GLOBAL_AS const void*)(g0 + (size_t)t * HIDDEN),
                    (LDS_AS void*)&ring[(slot + u) * 64], 4, 0, 0);
            }
            // all but the newest 32 loads have landed => chunks <= c-1 done
            __builtin_amdgcn_s_waitcnt(WAITCNT_VMCNT(32));
            __hip_atomic_store(&prod_c, c, __ATOMIC_RELEASE,
                               __HIP_MEMORY_SCOPE_WORKGROUP);
        }
        __builtin_amdgcn_s_waitcnt(WAITCNT_VMCNT(0));
        __hip_atomic_store(&prod_c, NCHK, __ATOMIC_RELEASE,
                           __HIP_MEMORY_SCOPE_WORKGROUP);
    } else {
        // ---------------- consumer ----------------
        // exp(-0.05), exp(-0.2) correctly rounded fp32 (match np.exp)
        const float am = 0.95122942450071400910f;
        const float as = 0.81873075307798185867f;
        float v = 0.0f, s = 0.0f;
        float* o0 = O + base + lane;

        #pragma unroll 1
        for (int c = 0; c < NCHK; ++c) {
            while (__hip_atomic_load(&prod_c, __ATOMIC_ACQUIRE,
                                     __HIP_MEMORY_SCOPE_WORKGROUP) < c + 1)
                __builtin_amdgcn_s_sleep(1);
            const int slot = (c & (RINGC - 1)) * SCH;
            // batch all 32 LDS reads first (bank = lane%32 -> 2-way = free),
            // then run the dependent chain on registers
            float x[SCH];
            #pragma unroll
            for (int u = 0; u < SCH; ++u)
                x[u] = ring[(slot + u) * 64 + lane];
            #pragma unroll
            for (int u = 0; u < SCH; ++u) {
                // separate mul/add roundings to match numpy (no FMA fusion)
                s = __fadd_rn(__fmul_rn(as, s), x[u]);
                v = __fadd_rn(__fmul_rn(am, v), s);
                const float o = (v > 1.0f) ? 1.0f : 0.0f;
                v = __fsub_rn(v, o);
                o0[(size_t)(c * SCH + u) * HIDDEN] = o;
            }
            __hip_atomic_store(&cons_c, c + 1, __ATOMIC_RELEASE,
                               __HIP_MEMORY_SCOPE_WORKGROUP);
        }
    }
}

extern "C" void kernel_launch(void* const* d_in, const int* in_sizes, int n_in,
                              void* d_out, int out_size, void* d_ws, size_t ws_size,
                              hipStream_t stream) {
    const float* spikes = (const float*)d_in[0];   // [32, 1024, 512]
    const float* W      = (const float*)d_in[1];   // [512, 512]
    const float* bias   = (const float*)d_in[2];   // [512]
    float* out  = (float*)d_out;                   // [32, 1024, 512]
    float* I_in = (float*)d_ws;                    // 64 MiB scratch

    zero_flags_kernel<<<dim3((NGEMM + 255) / 256), 256, 0, stream>>>();
    fused_kernel<<<dim3(NGEMM + NSCAN), 256, 0, stream>>>(spikes, W, bias, I_in, out);
}

// Round 4
// 311.758 us; speedup vs baseline: 1.2115x; 1.1319x over previous
//
#include <hip/hip_runtime.h>

// Problem constants (fixed by the reference)
constexpr int BATCH  = 32;
constexpr int TIME   = 1024;
constexpr int IN_DIM = 512;
constexpr int HIDDEN = 512;

constexpr int GM = BATCH * TIME;   // 32768  (GEMM M)
constexpr int GN = HIDDEN;         // 512    (GEMM N)
constexpr int GK = IN_DIM;         // 512    (GEMM K)

// ---------------- Phase 1: fp32 SGEMM with bias ----------------
// 128x128x16, 256 threads, 8x8 microtile, BOTH operands via LDS.
// Champion config (203-208us, VALUBusy 68%, VGPR 52, 8 blocks/CU max TLP).
// KEEP VERBATIM — 10 rounds of variants all regressed.
constexpr int BM = 128;
constexpr int BN = 128;
constexpr int BK = 16;
constexpr int LDAs = BM + 4;   // padded (2-way LDS alias only = free)
constexpr int LDBs = BN + 4;

__global__ __launch_bounds__(256) void sgemm_bias_kernel(
    const float* __restrict__ A,     // [GM, GK]
    const float* __restrict__ B,     // [GK, GN]
    const float* __restrict__ bias,  // [GN]
    float* __restrict__ C)           // [GM, GN]
{
    __shared__ __align__(16) float As[BK * LDAs];
    __shared__ __align__(16) float Bs[BK * LDBs];

    const int tid = threadIdx.x;           // 0..255
    const int bm  = blockIdx.x * BM;       // M-tile (256): same-A blocks are
    const int bn  = blockIdx.y * BN;       // 256 apart -> same XCD (L2 reuse)

    const int w    = tid >> 6;
    const int lane = tid & 63;
    const int row0 = (w >> 1) * 64 + (lane >> 3) * 8;
    const int col0 = (w & 1)  * 64 + (lane & 7)  * 8;

    const int ar0 = tid >> 2;              // A row for quad 0 (0..63), +64
    const int ac  = (tid & 3) << 2;        // A col within K-tile (0..12)
    const int br0 = tid >> 5;              // B row for quad 0 (0..7), +8
    const int bc  = (tid & 31) << 2;       // B col within N-tile (0..124)

    float acc[8][8];
    #pragma unroll
    for (int i = 0; i < 8; ++i)
        #pragma unroll
        for (int j = 0; j < 8; ++j) acc[i][j] = 0.0f;

    #pragma unroll 1
    for (int k0 = 0; k0 < GK; k0 += BK) {
        float4 va0 = *reinterpret_cast<const float4*>(A + (size_t)(bm + ar0) * GK + k0 + ac);
        float4 va1 = *reinterpret_cast<const float4*>(A + (size_t)(bm + ar0 + 64) * GK + k0 + ac);
        float4 vb0 = *reinterpret_cast<const float4*>(B + (size_t)(k0 + br0) * GN + bn + bc);
        float4 vb1 = *reinterpret_cast<const float4*>(B + (size_t)(k0 + br0 + 8) * GN + bn + bc);

        __syncthreads();   // previous tile's compute done before overwrite

        As[(ac + 0) * LDAs + ar0] = va0.x;
        As[(ac + 1) * LDAs + ar0] = va0.y;
        As[(ac + 2) * LDAs + ar0] = va0.z;
        As[(ac + 3) * LDAs + ar0] = va0.w;
        As[(ac + 0) * LDAs + ar0 + 64] = va1.x;
        As[(ac + 1) * LDAs + ar0 + 64] = va1.y;
        As[(ac + 2) * LDAs + ar0 + 64] = va1.z;
        As[(ac + 3) * LDAs + ar0 + 64] = va1.w;
        *reinterpret_cast<float4*>(&Bs[br0 * LDBs + bc]) = vb0;
        *reinterpret_cast<float4*>(&Bs[(br0 + 8) * LDBs + bc]) = vb1;

        __syncthreads();

        #pragma unroll
        for (int kk = 0; kk < BK; ++kk) {
            const float4 a0 = *reinterpret_cast<const float4*>(&As[kk * LDAs + row0]);
            const float4 a1 = *reinterpret_cast<const float4*>(&As[kk * LDAs + row0 + 4]);
            const float4 b0 = *reinterpret_cast<const float4*>(&Bs[kk * LDBs + col0]);
            const float4 b1 = *reinterpret_cast<const float4*>(&Bs[kk * LDBs + col0 + 4]);
            const float arr[8] = {a0.x, a0.y, a0.z, a0.w, a1.x, a1.y, a1.z, a1.w};
            const float brr[8] = {b0.x, b0.y, b0.z, b0.w, b1.x, b1.y, b1.z, b1.w};
            #pragma unroll
            for (int i = 0; i < 8; ++i)
                #pragma unroll
                for (int j = 0; j < 8; ++j)
                    acc[i][j] = fmaf(arr[i], brr[j], acc[i][j]);
        }
    }

    // ---- epilogue: add bias (separate fp32 add, like numpy), store ----
    #pragma unroll
    for (int i = 0; i < 8; ++i) {
        const size_t r = (size_t)(bm + row0 + i);
        #pragma unroll
        for (int j = 0; j < 8; j += 4) {
            float4 v;
            v.x = __fadd_rn(acc[i][j + 0], bias[bn + col0 + j + 0]);
            v.y = __fadd_rn(acc[i][j + 1], bias[bn + col0 + j + 1]);
            v.z = __fadd_rn(acc[i][j + 2], bias[bn + col0 + j + 2]);
            v.w = __fadd_rn(acc[i][j + 3], bias[bn + col0 + j + 3]);
            *reinterpret_cast<float4*>(&C[r * GN + bn + col0 + j]) = v;
        }
    }
}

// ---------------- Phase 2: LIF scan v2 — ring-free, register-pipelined ----
// Theory (R4): the 87us champion was PROTOCOL-bound (per-chunk LDS
// producer/consumer handshake + DMA retirement ~6500 cyc/chunk), not
// hardware-bound. Per-lane VALU chain is only ~3.4us; traffic floor is
// ~20us (128 MiB r+w at 6.3 TB/s). This version: one wave per
// (b, 64-h column), depth-1 register double buffer (xa/xb, static
// indices only — runtime-indexed arrays go to scratch), coalesced
// 256B loads, burst stores. The compiler's counted vmcnt handles the
// latency overlap (loads for chunk c+1 issued before chunk c's chain).
// Arithmetic bit-identical to champion: separate __fmul_rn/__fadd_rn.
constexpr int SCH  = 32;             // timesteps per chunk
constexpr int NCHK = TIME / SCH;     // 32 chunks

__global__ __launch_bounds__(64) void lif_scan_v2(
    const float* __restrict__ I,   // [B, T, H]
    float* __restrict__ O)         // [B, T, H]
{
    const int blk  = blockIdx.x;           // 0..255
    const int b    = blk >> 3;             // 8 blocks per batch row
    const int h0   = (blk & 7) * 64;
    const int lane = threadIdx.x;          // 0..63
    const size_t base = (size_t)b * TIME * HIDDEN + h0 + lane;
    const float* g0 = I + base;
    float*       o0 = O + base;

    // exp(-0.05), exp(-0.2) correctly rounded fp32 (match np.exp)
    const float am = 0.95122942450071400910f;
    const float as = 0.81873075307798185867f;
    float v = 0.0f, s = 0.0f;

    float xa[SCH], xb[SCH], ob[SCH];

    // prefetch chunk 0
    #pragma unroll
    for (int u = 0; u < SCH; ++u)
        xa[u] = g0[(size_t)u * HIDDEN];

    #pragma unroll 1
    for (int c = 0; c < NCHK; c += 2) {
        // issue chunk c+1 loads before consuming chunk c (latency overlap)
        #pragma unroll
        for (int u = 0; u < SCH; ++u)
            xb[u] = g0[(size_t)((c + 1) * SCH + u) * HIDDEN];

        // process chunk c from xa (separate mul/add roundings, no FMA fusion)
        #pragma unroll
        for (int u = 0; u < SCH; ++u) {
            s = __fadd_rn(__fmul_rn(as, s), xa[u]);
            v = __fadd_rn(__fmul_rn(am, v), s);
            const float o = (v > 1.0f) ? 1.0f : 0.0f;
            v = __fsub_rn(v, o);
            ob[u] = o;
        }
        #pragma unroll
        for (int u = 0; u < SCH; ++u)
            o0[(size_t)(c * SCH + u) * HIDDEN] = ob[u];

        // issue chunk c+2 loads before consuming chunk c+1
        if (c + 2 < NCHK) {
            #pragma unroll
            for (int u = 0; u < SCH; ++u)
                xa[u] = g0[(size_t)((c + 2) * SCH + u) * HIDDEN];
        }

        // process chunk c+1 from xb
        #pragma unroll
        for (int u = 0; u < SCH; ++u) {
            s = __fadd_rn(__fmul_rn(as, s), xb[u]);
            v = __fadd_rn(__fmul_rn(am, v), s);
            const float o = (v > 1.0f) ? 1.0f : 0.0f;
            v = __fsub_rn(v, o);
            ob[u] = o;
        }
        #pragma unroll
        for (int u = 0; u < SCH; ++u)
            o0[(size_t)((c + 1) * SCH + u) * HIDDEN] = ob[u];
    }
}

extern "C" void kernel_launch(void* const* d_in, const int* in_sizes, int n_in,
                              void* d_out, int out_size, void* d_ws, size_t ws_size,
                              hipStream_t stream) {
    const float* spikes = (const float*)d_in[0];   // [32, 1024, 512]
    const float* W      = (const float*)d_in[1];   // [512, 512]
    const float* bias   = (const float*)d_in[2];   // [512]
    float* out  = (float*)d_out;                   // [32, 1024, 512]
    float* I_in = (float*)d_ws;                    // 64 MiB scratch

    dim3 g1(GM / BM, GN / BN);                     // (256, 4)
    sgemm_bias_kernel<<<g1, 256, 0, stream>>>(spikes, W, bias, I_in);

    lif_scan_v2<<<BATCH * HIDDEN / 64, 64, 0, stream>>>(I_in, out);
}

// Round 5
// 310.619 us; speedup vs baseline: 1.2159x; 1.0037x over previous
//
#include <hip/hip_runtime.h>

// Problem constants (fixed by the reference)
constexpr int BATCH  = 32;
constexpr int TIME   = 1024;
constexpr int IN_DIM = 512;
constexpr int HIDDEN = 512;

constexpr int GM = BATCH * TIME;   // 32768  (GEMM M)
constexpr int GN = HIDDEN;         // 512    (GEMM N)
constexpr int GK = IN_DIM;         // 512    (GEMM K)

// ---------------- Phase 1: fp32 SGEMM with bias ----------------
// 128x128x16, 256 threads, 8x8 microtile, BOTH operands via LDS.
// Champion config (203-208us, VALUBusy 68%, VGPR 52, 8 blocks/CU max TLP).
// KEEP VERBATIM — 10 rounds of variants all regressed.
constexpr int BM = 128;
constexpr int BN = 128;
constexpr int BK = 16;
constexpr int LDAs = BM + 4;   // padded (2-way LDS alias only = free)
constexpr int LDBs = BN + 4;

__global__ __launch_bounds__(256) void sgemm_bias_kernel(
    const float* __restrict__ A,     // [GM, GK]
    const float* __restrict__ B,     // [GK, GN]
    const float* __restrict__ bias,  // [GN]
    float* __restrict__ C)           // [GM, GN]
{
    __shared__ __align__(16) float As[BK * LDAs];
    __shared__ __align__(16) float Bs[BK * LDBs];

    const int tid = threadIdx.x;           // 0..255
    const int bm  = blockIdx.x * BM;       // M-tile (256): same-A blocks are
    const int bn  = blockIdx.y * BN;       // 256 apart -> same XCD (L2 reuse)

    const int w    = tid >> 6;
    const int lane = tid & 63;
    const int row0 = (w >> 1) * 64 + (lane >> 3) * 8;
    const int col0 = (w & 1)  * 64 + (lane & 7)  * 8;

    const int ar0 = tid >> 2;              // A row for quad 0 (0..63), +64
    const int ac  = (tid & 3) << 2;        // A col within K-tile (0..12)
    const int br0 = tid >> 5;              // B row for quad 0 (0..7), +8
    const int bc  = (tid & 31) << 2;       // B col within N-tile (0..124)

    float acc[8][8];
    #pragma unroll
    for (int i = 0; i < 8; ++i)
        #pragma unroll
        for (int j = 0; j < 8; ++j) acc[i][j] = 0.0f;

    #pragma unroll 1
    for (int k0 = 0; k0 < GK; k0 += BK) {
        float4 va0 = *reinterpret_cast<const float4*>(A + (size_t)(bm + ar0) * GK + k0 + ac);
        float4 va1 = *reinterpret_cast<const float4*>(A + (size_t)(bm + ar0 + 64) * GK + k0 + ac);
        float4 vb0 = *reinterpret_cast<const float4*>(B + (size_t)(k0 + br0) * GN + bn + bc);
        float4 vb1 = *reinterpret_cast<const float4*>(B + (size_t)(k0 + br0 + 8) * GN + bn + bc);

        __syncthreads();   // previous tile's compute done before overwrite

        As[(ac + 0) * LDAs + ar0] = va0.x;
        As[(ac + 1) * LDAs + ar0] = va0.y;
        As[(ac + 2) * LDAs + ar0] = va0.z;
        As[(ac + 3) * LDAs + ar0] = va0.w;
        As[(ac + 0) * LDAs + ar0 + 64] = va1.x;
        As[(ac + 1) * LDAs + ar0 + 64] = va1.y;
        As[(ac + 2) * LDAs + ar0 + 64] = va1.z;
        As[(ac + 3) * LDAs + ar0 + 64] = va1.w;
        *reinterpret_cast<float4*>(&Bs[br0 * LDBs + bc]) = vb0;
        *reinterpret_cast<float4*>(&Bs[(br0 + 8) * LDBs + bc]) = vb1;

        __syncthreads();

        #pragma unroll
        for (int kk = 0; kk < BK; ++kk) {
            const float4 a0 = *reinterpret_cast<const float4*>(&As[kk * LDAs + row0]);
            const float4 a1 = *reinterpret_cast<const float4*>(&As[kk * LDAs + row0 + 4]);
            const float4 b0 = *reinterpret_cast<const float4*>(&Bs[kk * LDBs + col0]);
            const float4 b1 = *reinterpret_cast<const float4*>(&Bs[kk * LDBs + col0 + 4]);
            const float arr[8] = {a0.x, a0.y, a0.z, a0.w, a1.x, a1.y, a1.z, a1.w};
            const float brr[8] = {b0.x, b0.y, b0.z, b0.w, b1.x, b1.y, b1.z, b1.w};
            #pragma unroll
            for (int i = 0; i < 8; ++i)
                #pragma unroll
                for (int j = 0; j < 8; ++j)
                    acc[i][j] = fmaf(arr[i], brr[j], acc[i][j]);
        }
    }

    // ---- epilogue: add bias (separate fp32 add, like numpy), store ----
    #pragma unroll
    for (int i = 0; i < 8; ++i) {
        const size_t r = (size_t)(bm + row0 + i);
        #pragma unroll
        for (int j = 0; j < 8; j += 4) {
            float4 v;
            v.x = __fadd_rn(acc[i][j + 0], bias[bn + col0 + j + 0]);
            v.y = __fadd_rn(acc[i][j + 1], bias[bn + col0 + j + 1]);
            v.z = __fadd_rn(acc[i][j + 2], bias[bn + col0 + j + 2]);
            v.w = __fadd_rn(acc[i][j + 3], bias[bn + col0 + j + 3]);
            *reinterpret_cast<float4*>(&C[r * GN + bn + col0 + j]) = v;
        }
    }
}

// ---------------- Phase 2: LIF scan v3 — depth-4 register pipeline ----
// R4 post-mortem: ring-DMA (87us) and depth-2 register (95us) tie =>
// bottleneck is bytes-in-flight (Little's law), not protocol. Both kept
// ~<=32 loads/wave outstanding with full drains. v3: 4 rotating chunk
// buffers (static indexing only) so ~3 chunks = 96 loads are REQUESTED
// in flight; HW pins at the vmcnt cap (~63 outstanding x 256B x 256
// waves = 4 MB in flight -> ~10 TB/s Little ceiling). Scan should drop
// toward the per-CU BW floor (~21us) + chain overhead.
// Arithmetic bit-identical: separate __fmul_rn/__fadd_rn, exact constants.
constexpr int SCH  = 32;             // timesteps per chunk
constexpr int NCHK = TIME / SCH;     // 32 chunks

#define LOAD_CHUNK(buf, c)                                              \
    {                                                                   \
        const float* p_ = g0 + (size_t)(c) * SCH * HIDDEN;              \
        _Pragma("unroll")                                               \
        for (int u = 0; u < SCH; ++u)                                   \
            buf[u] = p_[(size_t)u * HIDDEN];                            \
    }

#define PROC_CHUNK(buf, c)                                              \
    {                                                                   \
        _Pragma("unroll")                                               \
        for (int u = 0; u < SCH; ++u) {                                 \
            s = __fadd_rn(__fmul_rn(as, s), buf[u]);                    \
            v = __fadd_rn(__fmul_rn(am, v), s);                         \
            const float o_ = (v > 1.0f) ? 1.0f : 0.0f;                  \
            v = __fsub_rn(v, o_);                                       \
            ob[u] = o_;                                                 \
        }                                                               \
        float* q_ = o0 + (size_t)(c) * SCH * HIDDEN;                    \
        _Pragma("unroll")                                               \
        for (int u = 0; u < SCH; ++u)                                   \
            q_[(size_t)u * HIDDEN] = ob[u];                             \
    }

__global__ __launch_bounds__(64) void lif_scan_v3(
    const float* __restrict__ I,   // [B, T, H]
    float* __restrict__ O)         // [B, T, H]
{
    const int blk  = blockIdx.x;           // 0..255
    const int b    = blk >> 3;             // 8 blocks per batch row
    const int h0   = (blk & 7) * 64;
    const int lane = threadIdx.x;          // 0..63
    const size_t base = (size_t)b * TIME * HIDDEN + h0 + lane;
    const float* g0 = I + base;
    float*       o0 = O + base;

    // exp(-0.05), exp(-0.2) correctly rounded fp32 (match np.exp)
    const float am = 0.95122942450071400910f;
    const float as = 0.81873075307798185867f;
    float v = 0.0f, s = 0.0f;

    float xA[SCH], xB[SCH], xC[SCH], xD[SCH], ob[SCH];

    // prologue: request 4 chunks (128 loads; HW caps outstanding at ~63)
    LOAD_CHUNK(xA, 0)
    LOAD_CHUNK(xB, 1)
    LOAD_CHUNK(xC, 2)
    LOAD_CHUNK(xD, 3)

    #pragma unroll 1
    for (int c = 0; c < NCHK; c += 4) {
        PROC_CHUNK(xA, c)
        if (c + 4 < NCHK) LOAD_CHUNK(xA, c + 4)
        PROC_CHUNK(xB, c + 1)
        if (c + 5 < NCHK) LOAD_CHUNK(xB, c + 5)
        PROC_CHUNK(xC, c + 2)
        if (c + 6 < NCHK) LOAD_CHUNK(xC, c + 6)
        PROC_CHUNK(xD, c + 3)
        if (c + 7 < NCHK) LOAD_CHUNK(xD, c + 7)
    }
}

extern "C" void kernel_launch(void* const* d_in, const int* in_sizes, int n_in,
                              void* d_out, int out_size, void* d_ws, size_t ws_size,
                              hipStream_t stream) {
    const float* spikes = (const float*)d_in[0];   // [32, 1024, 512]
    const float* W      = (const float*)d_in[1];   // [512, 512]
    const float* bias   = (const float*)d_in[2];   // [512]
    float* out  = (float*)d_out;                   // [32, 1024, 512]
    float* I_in = (float*)d_ws;                    // 64 MiB scratch

    dim3 g1(GM / BM, GN / BN);                     // (256, 4)
    sgemm_bias_kernel<<<g1, 256, 0, stream>>>(spikes, W, bias, I_in);

    lif_scan_v3<<<BATCH * HIDDEN / 64, 64, 0, stream>>>(I_in, out);
}